// Round 8
// baseline (384.534 us; speedup 1.0000x reference)
//
#include <hip/hip_runtime.h>

// Problem constants (fixed by setup_inputs: B=2,C=32,H=128,W=240, max_disp=192 -> D=48)
constexpr int B  = 2;
constexpr int C  = 32;
constexpr int H  = 128;
constexpr int W  = 240;
constexpr int D  = 48;
constexpr int C2 = 2 * C;            // 64 output channels
constexpr int W4 = W / 4;            // 60 float4 per row
constexpr int W8 = W4 / 2;           // 30 quad-pairs per row
constexpr int DSTRIDE = H * W4;      // float4 stride between consecutive d slices
constexpr int NPLANES = B * C2;      // 128 (b,c2) planes
constexpr int BPP = H * W8 / 256;    // 15 blocks per plane (pair-granular)
constexpr int NXCD = 8;
constexpr int PPX = NPLANES / NXCD;  // 16 planes per XCD
constexpr int GRID = NPLANES * BPP;  // 1920 blocks

// native vector type for __builtin_nontemporal_store (HIP_vector_type is rejected)
typedef float nfloat4 __attribute__((ext_vector_type(4)));

__device__ __forceinline__ void nt_store(float4* p, float x, float y, float z, float w)
{
    nfloat4 v = { x, y, z, w };
    __builtin_nontemporal_store(v, reinterpret_cast<nfloat4*>(p));
}

__global__ __launch_bounds__(256)
void cost_volume_kernel(const float* __restrict__ left,
                        const float* __restrict__ right,
                        float4* __restrict__ out)
{
    // XCD-partitioned plane assignment (kept from R7, neutral but harmless).
    int bid   = blockIdx.x;
    int xcd   = bid & (NXCD - 1);
    int j     = bid >> 3;              // 0..239
    int plane = xcd * PPX + j / BPP;   // 0..127
    int inner = j % BPP;               // 0..14
    int c2    = plane & (C2 - 1);
    int b     = plane >> 6;

    int p  = inner * 256 + (int)threadIdx.x;  // pair index in plane, 0..3839
    int h  = p / W8;
    int w8 = p - h * W8;
    int w0 = w8 * 8;                   // first output float of the pair

    // each thread writes quads [2*w8, 2*w8+1] of every d-slice: 32B burst
    float4* outp = out + ((size_t)plane * D * H + h) * W4 + 2 * w8;

    if (c2 < C) {
        // ---- left volume: two loads, 48 x 32B masked nontemporal bursts ----
        const float4* srow = reinterpret_cast<const float4*>(
            left + ((b * C + c2) * H + h) * W);
        float4 A  = srow[2 * w8];
        float4 A2 = srow[2 * w8 + 1];
#pragma unroll
        for (int d = 0; d < D; ++d) {
            nt_store(outp + d * DSTRIDE,
                     (w0 + 0 >= d) ? A.x : 0.0f,
                     (w0 + 1 >= d) ? A.y : 0.0f,
                     (w0 + 2 >= d) ? A.z : 0.0f,
                     (w0 + 3 >= d) ? A.w : 0.0f);
            nt_store(outp + d * DSTRIDE + 1,
                     (w0 + 4 >= d) ? A2.x : 0.0f,
                     (w0 + 5 >= d) ? A2.y : 0.0f,
                     (w0 + 6 >= d) ? A2.z : 0.0f,
                     (w0 + 7 >= d) ? A2.w : 0.0f);
        }
    } else {
        // ---- right volume: 3-quad sliding window, 4 d's per new load ----
        // Group g (d = 4g+s, s=0..3): sources span quads Lo=2w8-g-1,
        // Mid=2w8-g, Hi=2w8-g+1. win12 = Lo||Mid||Hi; output float j (0..7)
        // at shift s is win[4 + j - s] (compile-time after unroll).
        // Negative quad indices clamp to 0; poisoned elements provably feed
        // only mask-zeroed outputs (elem reading quad slot with true index
        // < 0 has source index w0+j-d < 0 <=> w0+j < d <=> masked).
        const float4* srow = reinterpret_cast<const float4*>(
            right + ((b * C + (c2 - C)) * H + h) * W);
        float4 Mid = srow[2 * w8];
        float4 Hi  = srow[2 * w8 + 1];
#pragma unroll
        for (int g = 0; g < D / 4; ++g) {
            int ql  = 2 * w8 - g - 1;
            float4 Lo = srow[ql < 0 ? 0 : ql];
            float win[12] = { Lo.x, Lo.y, Lo.z, Lo.w,
                              Mid.x, Mid.y, Mid.z, Mid.w,
                              Hi.x, Hi.y, Hi.z, Hi.w };
#pragma unroll
            for (int s = 0; s < 4; ++s) {
                const int d = 4 * g + s;
                nt_store(outp + d * DSTRIDE,
                         (w0 + 0 >= d) ? win[4 + 0 - s] : 0.0f,
                         (w0 + 1 >= d) ? win[4 + 1 - s] : 0.0f,
                         (w0 + 2 >= d) ? win[4 + 2 - s] : 0.0f,
                         (w0 + 3 >= d) ? win[4 + 3 - s] : 0.0f);
                nt_store(outp + d * DSTRIDE + 1,
                         (w0 + 4 >= d) ? win[4 + 4 - s] : 0.0f,
                         (w0 + 5 >= d) ? win[4 + 5 - s] : 0.0f,
                         (w0 + 6 >= d) ? win[4 + 6 - s] : 0.0f,
                         (w0 + 7 >= d) ? win[4 + 7 - s] : 0.0f);
            }
            Hi = Mid;  // slide window down one quad
            Mid = Lo;
        }
    }
}

extern "C" void kernel_launch(void* const* d_in, const int* in_sizes, int n_in,
                              void* d_out, int out_size, void* d_ws, size_t ws_size,
                              hipStream_t stream)
{
    const float* left  = (const float*)d_in[0];
    const float* right = (const float*)d_in[1];
    float4* out = (float4*)d_out;

    cost_volume_kernel<<<GRID, 256, 0, stream>>>(left, right, out);
}

// Round 9
// 149.676 us; speedup vs baseline: 2.5691x; 2.5691x over previous
//
#include <hip/hip_runtime.h>

// Problem constants (fixed by setup_inputs: B=2,C=32,H=128,W=240, max_disp=192 -> D=48)
constexpr int B  = 2;
constexpr int C  = 32;
constexpr int H  = 128;
constexpr int W  = 240;
constexpr int D  = 48;
constexpr int C2 = 2 * C;            // 64 output channels
constexpr int W4 = W / 4;            // 60 float4 per row
constexpr int QPS = H * W4;          // 7680 quads per (plane,d) slice
constexpr int HROWS = 64;            // rows per block (half plane)
constexpr int QPB = HROWS * W4;      // 3840 quads staged per block (60 KB)
constexpr int BLOCK = 256;
constexpr int KS = QPB / BLOCK;      // 15 quads per thread per slice
constexpr int NDQ = D / 4;           // 12 d-quads
constexpr int GRID = B * C2 * NDQ * 2;  // 3072 blocks

// native vector type for __builtin_nontemporal_store (HIP_vector_type is rejected)
typedef float nfloat4 __attribute__((ext_vector_type(4)));

__device__ __forceinline__ void nt_store(float4* p, float x, float y, float z, float w)
{
    nfloat4 v = { x, y, z, w };
    __builtin_nontemporal_store(v, reinterpret_cast<nfloat4*>(p));
}

__global__ __launch_bounds__(256)
void cost_volume_kernel(const float* __restrict__ left,
                        const float* __restrict__ right,
                        float4* __restrict__ out)
{
    __shared__ float4 lds[QPB];      // 61,440 B -> 2 blocks/CU resident

    // bid -> (plane, dq, rh); consecutive bid = consecutive 60 KB output
    // regions, so the chip-wide write front is dense and linear (fill-like).
    int bid   = blockIdx.x;
    int rh    = bid & 1;
    int t     = bid >> 1;
    int dq    = t % NDQ;             // d = 4*dq + dd, dd in [0,4)
    int plane = t / NDQ;             // 0..127
    int c2    = plane & (C2 - 1);
    int b     = plane >> 6;

    // stage 64 input rows (this half-plane) into LDS, coalesced 4 KB/iter
    const float* baseimg = (c2 < C)
        ? left  + (size_t)((b * C + c2)       * H) * W
        : right + (size_t)((b * C + (c2 - C)) * H) * W;
    const float4* img = reinterpret_cast<const float4*>(baseimg + rh * HROWS * W);
#pragma unroll
    for (int k = 0; k < KS; ++k) {
        int qi = (int)threadIdx.x + k * BLOCK;
        lds[qi] = img[qi];
    }
    __syncthreads();

    // output: 4 consecutive d-slices of this half-plane, each a 60 KB
    // linear stream (k sweeps front-to-back, lanes contiguous per store)
    float4* outbase = out + ((size_t)plane * D + 4 * dq) * QPS + rh * QPB;

    if (c2 < C) {
        // ---- left half: masked copy of the staged rows ----
#pragma unroll
        for (int k = 0; k < KS; ++k) {
            int qi  = (int)threadIdx.x + k * BLOCK;
            int row = qi / W4;
            int w4  = qi - row * W4;
            int m   = w4 * 4 - 4 * dq;   // elem j at d=4dq+dd unmasked iff m+j >= dd
            float4 v = lds[qi];
#pragma unroll
            for (int dd = 0; dd < 4; ++dd) {
                nt_store(outbase + dd * QPS + qi,
                         (m + 0 >= dd) ? v.x : 0.0f,
                         (m + 1 >= dd) ? v.y : 0.0f,
                         (m + 2 >= dd) ? v.z : 0.0f,
                         (m + 3 >= dd) ? v.w : 0.0f);
            }
        }
    } else {
        // ---- right half: shifted copy; all 4 dd share the same 2 LDS quads
        // (g = dq uniform), shift s = dd is a compile-time unroll index.
        // win[4+j-dd] picks elem j; clamped quad indices (<0) feed only
        // mask-zeroed elements: hq<0 => w0+3 < 4dq <= d (all masked);
        // lq<0 & hq>=0 => w4==dq, Lo-sourced j<dd have 4*0+j-dd<0 (masked).
#pragma unroll
        for (int k = 0; k < KS; ++k) {
            int qi  = (int)threadIdx.x + k * BLOCK;
            int row = qi / W4;
            int w4  = qi - row * W4;
            int m   = (w4 - dq) * 4;     // elem j at dd unmasked iff m+j >= dd
            int hq  = w4 - dq;
            int lq  = hq - 1;
            int rowbase = row * W4;
            float4 Hi = lds[rowbase + (hq < 0 ? 0 : hq)];
            float4 Lo = lds[rowbase + (lq < 0 ? 0 : lq)];
            float win[8] = { Lo.x, Lo.y, Lo.z, Lo.w, Hi.x, Hi.y, Hi.z, Hi.w };
#pragma unroll
            for (int dd = 0; dd < 4; ++dd) {
                nt_store(outbase + dd * QPS + qi,
                         (m + 0 >= dd) ? win[4 + 0 - dd] : 0.0f,
                         (m + 1 >= dd) ? win[4 + 1 - dd] : 0.0f,
                         (m + 2 >= dd) ? win[4 + 2 - dd] : 0.0f,
                         (m + 3 >= dd) ? win[4 + 3 - dd] : 0.0f);
            }
        }
    }
}

extern "C" void kernel_launch(void* const* d_in, const int* in_sizes, int n_in,
                              void* d_out, int out_size, void* d_ws, size_t ws_size,
                              hipStream_t stream)
{
    const float* left  = (const float*)d_in[0];
    const float* right = (const float*)d_in[1];
    float4* out = (float4*)d_out;

    cost_volume_kernel<<<GRID, BLOCK, 0, stream>>>(left, right, out);
}

// Round 10
// 141.353 us; speedup vs baseline: 2.7204x; 1.0589x over previous
//
#include <hip/hip_runtime.h>

// Problem constants (fixed by setup_inputs: B=2,C=32,H=128,W=240, max_disp=192 -> D=48)
constexpr int B  = 2;
constexpr int C  = 32;
constexpr int H  = 128;
constexpr int W  = 240;
constexpr int D  = 48;
constexpr int C2 = 2 * C;            // 64 output channels
constexpr int W4 = W / 4;            // 60 float4 per row
constexpr int DSTRIDE = H * W4;      // float4 stride between consecutive d slices
constexpr int NPLANES = B * C2;      // 128 (b,c2) planes
constexpr int BPP = H * W4 / 256;    // 30 blocks per plane
constexpr int NXCD = 8;
constexpr int PPX = NPLANES / NXCD;  // 16 planes per XCD
constexpr int GRID = NPLANES * BPP;  // 3840 blocks

// native vector type for __builtin_nontemporal_store (HIP_vector_type is rejected)
typedef float nfloat4 __attribute__((ext_vector_type(4)));

__device__ __forceinline__ void nt_store(float4* p, float x, float y, float z, float w)
{
    nfloat4 v = { x, y, z, w };
    __builtin_nontemporal_store(v, reinterpret_cast<nfloat4*>(p));
}

__global__ __launch_bounds__(256)
void cost_volume_kernel(const float* __restrict__ left,
                        const float* __restrict__ right,
                        float4* __restrict__ out)
{
    // XCD-partitioned plane assignment (from R7; neutral but harmless).
    int bid   = blockIdx.x;
    int xcd   = bid & (NXCD - 1);
    int j     = bid >> 3;              // 0..479
    int plane = xcd * PPX + j / BPP;   // 0..127
    int inner = j % BPP;               // 0..29
    int c2    = plane & (C2 - 1);
    int b     = plane >> 6;

    int q  = inner * 256 + (int)threadIdx.x;  // quad index in plane, 0..7679
    int h  = q / W4;
    int w4 = q - h * W4;
    int w0 = w4 * 4;

    // out float4 index = (((b*C2 + c2)*D + d)*H + h)*W4 + w4
    float4* outp = out + ((b * C2 + c2) * D * H + h) * W4 + w4;

    if (c2 < C) {
        // ---- left volume: one load, then a pure 48-store stream ----
        const float* src = left + ((b * C + c2) * H + h) * W;
        float4 vv = *reinterpret_cast<const float4*>(src + w0);
#pragma unroll
        for (int d = 0; d < D; ++d) {
            nt_store(outp + d * DSTRIDE,
                     (w0 + 0 >= d) ? vv.x : 0.0f,
                     (w0 + 1 >= d) ? vv.y : 0.0f,
                     (w0 + 2 >= d) ? vv.z : 0.0f,
                     (w0 + 3 >= d) ? vv.w : 0.0f);
        }
    } else {
        // ---- right volume: preload the ENTIRE 13-quad window, then a
        // pure 48-store stream with zero memory dependencies.
        // Store for d = 4g+s needs floats [w0-d .. w0-d+3] = quads
        // (w4-g-1, w4-g) = (P[g+1], P[g]) where P[i] = quad(w4-i).
        // All P indices are compile-time (unrolled) -> registers, no scratch.
        // Negative quad indices clamp to 0; poisoned elements feed only
        // mask-zeroed outputs (same proof as R3/R7: an element sourced from
        // a clamped quad has true source index w0+j-d < 0 <=> masked).
        const float4* srow = reinterpret_cast<const float4*>(
            right + ((b * C + (c2 - C)) * H + h) * W);
        float4 P[13];
#pragma unroll
        for (int i = 0; i < 13; ++i) {
            int qi = w4 - i;
            P[i] = srow[qi < 0 ? 0 : qi];
        }
#pragma unroll
        for (int g = 0; g < D / 4; ++g) {
            float win[8] = { P[g + 1].x, P[g + 1].y, P[g + 1].z, P[g + 1].w,
                             P[g].x,     P[g].y,     P[g].z,     P[g].w };
#pragma unroll
            for (int s = 0; s < 4; ++s) {
                const int d = 4 * g + s;
                nt_store(outp + d * DSTRIDE,
                         (w0 + 0 >= d) ? win[4 + 0 - s] : 0.0f,
                         (w0 + 1 >= d) ? win[4 + 1 - s] : 0.0f,
                         (w0 + 2 >= d) ? win[4 + 2 - s] : 0.0f,
                         (w0 + 3 >= d) ? win[4 + 3 - s] : 0.0f);
            }
        }
    }
}

extern "C" void kernel_launch(void* const* d_in, const int* in_sizes, int n_in,
                              void* d_out, int out_size, void* d_ws, size_t ws_size,
                              hipStream_t stream)
{
    const float* left  = (const float*)d_in[0];
    const float* right = (const float*)d_in[1];
    float4* out = (float4*)d_out;

    cost_volume_kernel<<<GRID, 256, 0, stream>>>(left, right, out);
}